// Round 4
// baseline (1962.047 us; speedup 1.0000x reference)
//
#include <hip/hip_runtime.h>

// Liquid-network scan: one block per batch row (B=128 blocks), 1024 threads.
// 4-way K-split: thread (j = tid&255, s = tid>>8) computes k in [s*64, s*64+64)
// for output column j via 32 readlane (SGPR broadcast) + 32 v_dot2_f32_f16.
// 4 waves/SIMD hide readlane->dot hazards and LDS latencies during the dot
// phase. Partials combine via part[4][256]; LN reduce is pure-VALU DPP on
// threads 0-255; h is stored pre-packed fp16x2 (DPP neighbor fetch +
// cvt_pkrtz) so the next step's broadcast source is one ds_read_b32.
// 3 barriers/step: [A] partials, [B] LN cross-wave sums, [C] new h + next x.

#define BB     128
#define TT     2048
#define DIN    16
#define HH     256
#define NAPP   10
#define NT     1024
#define DT_STEP 0.1f
#define LN_EPS_C 1e-5f

typedef _Float16 half2_t __attribute__((ext_vector_type(2)));

template<int CTRL>
__device__ __forceinline__ float dpp_mov0(float x) {
    // update_dpp(old=0, src, ctrl, row_mask=0xF, bank_mask=0xF, bound_ctrl=true)
    return __builtin_bit_cast(float,
        __builtin_amdgcn_update_dpp(0, __builtin_bit_cast(int, x), CTRL, 0xF, 0xF, true));
}

// After this, lane 63 holds the wave-wide sums of s1 and s2. (HW-verified r3.)
__device__ __forceinline__ void wave_reduce2(float& s1, float& s2) {
    s1 += dpp_mov0<0x111>(s1); s2 += dpp_mov0<0x111>(s2);  // row_shr:1
    s1 += dpp_mov0<0x112>(s1); s2 += dpp_mov0<0x112>(s2);  // row_shr:2
    s1 += dpp_mov0<0x114>(s1); s2 += dpp_mov0<0x114>(s2);  // row_shr:4
    s1 += dpp_mov0<0x118>(s1); s2 += dpp_mov0<0x118>(s2);  // row_shr:8
    s1 += dpp_mov0<0x142>(s1); s2 += dpp_mov0<0x142>(s2);  // row_bcast:15
    s1 += dpp_mov0<0x143>(s1); s2 += dpp_mov0<0x143>(s2);  // row_bcast:31
}

__device__ __forceinline__ half2_t as_h2(int v) { return __builtin_bit_cast(half2_t, v); }

__global__ __launch_bounds__(NT, 1)
void liquid_scan_kernel(const float* __restrict__ x,
                        const float* __restrict__ W_in,
                        const float* __restrict__ b_in,
                        const float* __restrict__ tau_param,
                        const float* __restrict__ W_rec,
                        const float* __restrict__ g_intra,
                        const float* __restrict__ b_intra,
                        const float* __restrict__ g_norm,
                        const float* __restrict__ b_norm,
                        const float* __restrict__ W_head,
                        const float* __restrict__ b_head,
                        float* __restrict__ out)
{
    const int tid  = threadIdx.x;
    const int b    = blockIdx.x;
    const int j    = tid & (HH - 1);
    const int s    = tid >> 8;        // k-split 0..3 (wave-uniform)
    const int wv   = tid >> 6;        // wave id 0..15
    const int lane = tid & 63;

    __shared__ float part[4][HH];                 // [1..3] partials; [0] reused at end
    __shared__ __align__(16) float wred[4][2];
    __shared__ __align__(16) float xbuf[2][DIN];
    __shared__ unsigned int hpk_lds[HH / 2];      // h packed as fp16 pairs

    // ---- packed recurrent weights: w2[p] = (W[s*64+2p][j], W[s*64+2p+1][j])
    half2_t w2[32];
    #pragma unroll
    for (int p = 0; p < 32; ++p) {
        const float wa = W_rec[(size_t)(s * 64 + 2 * p)     * HH + j];
        const float wb = W_rec[(size_t)(s * 64 + 2 * p + 1) * HH + j];
        half2_t t2; t2.x = (_Float16)wa; t2.y = (_Float16)wb;
        w2[p] = t2;
    }

    float win[DIN];
    float bi = 0.f;
    if (s == 1) {
        bi = b_in[j];
        #pragma unroll
        for (int k = 0; k < DIN; ++k) win[k] = W_in[j * DIN + k];
    }
    float gi = 0.f, bbi = 0.f, gn = 0.f, bn = 0.f, itau = 0.f;
    if (s == 0) {
        gi = g_intra[j]; bbi = b_intra[j]; gn = g_norm[j]; bn = b_norm[j];
        const float tp  = tau_param[j];
        const float tau = (tp > 20.f) ? tp : log1pf(__expf(tp));  // softplus
        itau = 1.f / tau;
    }

    float hj = 0.f;                                // state (meaningful on tid<256)
    if (tid < HH / 2) hpk_lds[tid] = 0u;           // h = 0
    const size_t xbase = (size_t)b * TT * DIN;
    if (tid < DIN) xbuf[0][tid] = x[xbase + tid];
    __syncthreads();

    const int pl = tid - (NT - DIN);   // prefetch lanes: last 16 threads (wave 15)

    for (int t = 0; t < TT; ++t) {
        // issue x prefetch for t+1 early; LDS write deferred to after barrier B
        float xv = 0.f;
        if (pl >= 0 && t + 1 < TT)
            xv = x[xbase + (size_t)(t + 1) * DIN + pl];

        // broadcast source: lane l (l&31) holds pair index s*32+(l&31)
        const int hpk = (int)hpk_lds[(s << 5) + (lane & 31)];

        // ---- K=64 dot: 32 readlane + 32 dot2, 4 independent chains
        float a0 = 0.f, a1 = 0.f, a2 = 0.f, a3 = 0.f;
        #pragma unroll
        for (int p = 0; p < 32; p += 4) {
            const int r0 = __builtin_amdgcn_readlane(hpk, p + 0);
            const int r1 = __builtin_amdgcn_readlane(hpk, p + 1);
            const int r2 = __builtin_amdgcn_readlane(hpk, p + 2);
            const int r3 = __builtin_amdgcn_readlane(hpk, p + 3);
            a0 = __builtin_amdgcn_fdot2(as_h2(r0), w2[p + 0], a0, false);
            a1 = __builtin_amdgcn_fdot2(as_h2(r1), w2[p + 1], a1, false);
            a2 = __builtin_amdgcn_fdot2(as_h2(r2), w2[p + 2], a2, false);
            a3 = __builtin_amdgcn_fdot2(as_h2(r3), w2[p + 3], a3, false);
        }
        float acc = (a0 + a1) + (a2 + a3);

        if (s == 1) {
            // fold input projection into this split's partial
            float uin = bi;
            const float4* xb = (const float4*)xbuf[t & 1];
            const float4 x0 = xb[0], x1 = xb[1], x2 = xb[2], x3 = xb[3];
            uin = fmaf(x0.x, win[0],  uin); uin = fmaf(x0.y, win[1],  uin);
            uin = fmaf(x0.z, win[2],  uin); uin = fmaf(x0.w, win[3],  uin);
            uin = fmaf(x1.x, win[4],  uin); uin = fmaf(x1.y, win[5],  uin);
            uin = fmaf(x1.z, win[6],  uin); uin = fmaf(x1.w, win[7],  uin);
            uin = fmaf(x2.x, win[8],  uin); uin = fmaf(x2.y, win[9],  uin);
            uin = fmaf(x2.z, win[10], uin); uin = fmaf(x2.w, win[11], uin);
            uin = fmaf(x3.x, win[12], uin); uin = fmaf(x3.y, win[13], uin);
            uin = fmaf(x3.z, win[14], uin); uin = fmaf(x3.w, win[15], uin);
            part[1][j] = acc + uin;
        } else if (s >= 2) {
            part[s][j] = acc;
        }
        __syncthreads();   // A: partials visible

        float u_carry = 0.f;
        if (tid < HH) {                     // waves 0-3, one per SIMD
            const float u = acc + (part[1][j] + part[2][j]) + part[3][j];
            u_carry = u;
            float s1 = u, s2 = u * u;
            wave_reduce2(s1, s2);
            if (lane == 63) { wred[wv][0] = s1; wred[wv][1] = s2; }
        }
        __syncthreads();   // B: cross-wave LN sums visible

        if (tid < HH) {
            const float4 ra = ((const float4*)wred)[0];
            const float4 rb = ((const float4*)wred)[1];
            const float S1 = (ra.x + ra.z) + (rb.x + rb.z);
            const float S2 = (ra.y + ra.w) + (rb.y + rb.w);
            const float mu  = S1 * (1.f / HH);
            const float var = S2 * (1.f / HH) - mu * mu;
            const float rs  = rsqrtf(var + LN_EPS_C);
            const float xn  = (u_carry - mu) * rs * gi + bbi;
            // tanh(x) = 1 - 2/(exp(2x)+1); saturates correctly via inf/0
            const float e = __expf(2.f * xn);
            const float f = 1.f - 2.f / (e + 1.f);
            float hn = hj + (f - hj * itau) * DT_STEP;
            hn = fminf(10.f, fmaxf(-10.f, hn));
            hj = hn;
            // even lane packs (h[j], h[j+1]) -> one dword (row_shl:1 = lane i gets lane i+1)
            const float hnb = __builtin_bit_cast(float,
                __builtin_amdgcn_update_dpp(0, __builtin_bit_cast(int, hn), 0x101, 0xF, 0xF, true));
            if (!(lane & 1))
                hpk_lds[j >> 1] = __builtin_bit_cast(unsigned int,
                                   __builtin_amdgcn_cvt_pkrtz(hn, hnb));
        } else if (pl >= 0 && t + 1 < TT) {
            xbuf[(t + 1) & 1][pl] = xv;   // vmcnt wait hidden under LN window
        }
        __syncthreads();   // C: new packed h + next x visible
    }

    // ---- final LayerNorm (g_norm, b_norm) + head ----
    if (tid < HH) {
        float s1 = hj, s2 = hj * hj;
        wave_reduce2(s1, s2);
        if (lane == 63) { wred[wv][0] = s1; wred[wv][1] = s2; }
    }
    __syncthreads();
    if (tid < HH) {
        const float4 ra = ((const float4*)wred)[0];
        const float4 rb = ((const float4*)wred)[1];
        const float S1 = (ra.x + ra.z) + (rb.x + rb.z);
        const float S2 = (ra.y + ra.w) + (rb.y + rb.w);
        const float mu  = S1 * (1.f / HH);
        const float var = S2 * (1.f / HH) - mu * mu;
        const float rs  = rsqrtf(var + LN_EPS_C);
        part[0][j] = (hj - mu) * rs * gn + bn;
    }
    __syncthreads();
    if (tid < NAPP) {
        float o = b_head[tid];
        for (int jj = 0; jj < HH; ++jj)
            o = fmaf(part[0][jj], W_head[jj * NAPP + tid], o);
        out[(size_t)b * NAPP + tid] = o;
    }
}

extern "C" void kernel_launch(void* const* d_in, const int* in_sizes, int n_in,
                              void* d_out, int out_size, void* d_ws, size_t ws_size,
                              hipStream_t stream) {
    const float* x       = (const float*)d_in[0];
    const float* W_in    = (const float*)d_in[1];
    const float* b_in    = (const float*)d_in[2];
    const float* tau     = (const float*)d_in[3];
    const float* W_rec   = (const float*)d_in[4];
    const float* g_intra = (const float*)d_in[5];
    const float* b_intra = (const float*)d_in[6];
    const float* g_norm  = (const float*)d_in[7];
    const float* b_norm  = (const float*)d_in[8];
    const float* W_head  = (const float*)d_in[9];
    const float* b_head  = (const float*)d_in[10];
    float* out = (float*)d_out;

    hipLaunchKernelGGL(liquid_scan_kernel, dim3(BB), dim3(NT), 0, stream,
                       x, W_in, b_in, tau, W_rec, g_intra, b_intra,
                       g_norm, b_norm, W_head, b_head, out);
}

// Round 5
// 1710.964 us; speedup vs baseline: 1.1467x; 1.1467x over previous
//
#include <hip/hip_runtime.h>

// Liquid-network scan: one block per batch row (B=128 blocks), 256 threads.
// Key change vs r4: NO global loads inside the scan loop. __syncthreads()
// drains vmcnt(0); the per-step x prefetch made every step's first barrier
// eat a full HBM-load latency. Whole x[b] (128 KB fp32) is staged in LDS once.
// Wave kq (=k-quarter) computes k in [64kq,64kq+64) for 4 j's per lane
// (j = 4*lane..4*lane+3): 32 readlane (SGPR broadcast, amortized over 4 j)
// + 128 v_dot2_f32_f16 + 16 input-proj fma. Partials combine via float4
// part[4][256] (contiguous b128 = conflict-free); wave 0 alone does the LN:
// in-wave DPP reduce (no cross-wave round trip), tanh, Euler update, fp16
// pack, one b64 h write. 2 barriers/step.

#define BB     128
#define TT     2048
#define DIN    16
#define HH     256
#define NAPP   10
#define NT     256
#define DT_STEP 0.1f
#define LN_EPS_C 1e-5f

typedef _Float16 half2_t __attribute__((ext_vector_type(2)));

template<int CTRL>
__device__ __forceinline__ float dpp_mov0(float x) {
    // update_dpp(old=0, src, ctrl, row_mask=0xF, bank_mask=0xF, bound_ctrl=true)
    return __builtin_bit_cast(float,
        __builtin_amdgcn_update_dpp(0, __builtin_bit_cast(int, x), CTRL, 0xF, 0xF, true));
}

// After this, lane 63 holds the wave-wide sums of s1 and s2. (HW-verified r3/r4.)
__device__ __forceinline__ void wave_reduce2(float& s1, float& s2) {
    s1 += dpp_mov0<0x111>(s1); s2 += dpp_mov0<0x111>(s2);  // row_shr:1
    s1 += dpp_mov0<0x112>(s1); s2 += dpp_mov0<0x112>(s2);  // row_shr:2
    s1 += dpp_mov0<0x114>(s1); s2 += dpp_mov0<0x114>(s2);  // row_shr:4
    s1 += dpp_mov0<0x118>(s1); s2 += dpp_mov0<0x118>(s2);  // row_shr:8
    s1 += dpp_mov0<0x142>(s1); s2 += dpp_mov0<0x142>(s2);  // row_bcast:15
    s1 += dpp_mov0<0x143>(s1); s2 += dpp_mov0<0x143>(s2);  // row_bcast:31
}

__device__ __forceinline__ half2_t as_h2(int v) { return __builtin_bit_cast(half2_t, v); }
__device__ __forceinline__ float rl63(float v) {
    return __builtin_bit_cast(float,
        __builtin_amdgcn_readlane(__builtin_bit_cast(int, v), 63));
}
__device__ __forceinline__ float softplus_f(float v) {
    return (v > 20.f) ? v : log1pf(__expf(v));
}

__global__ __launch_bounds__(NT, 1)
void liquid_scan_kernel(const float* __restrict__ x,
                        const float* __restrict__ W_in,
                        const float* __restrict__ b_in,
                        const float* __restrict__ tau_param,
                        const float* __restrict__ W_rec,
                        const float* __restrict__ g_intra,
                        const float* __restrict__ b_intra,
                        const float* __restrict__ g_norm,
                        const float* __restrict__ b_norm,
                        const float* __restrict__ W_head,
                        const float* __restrict__ b_head,
                        float* __restrict__ out)
{
    const int tid  = threadIdx.x;
    const int b    = blockIdx.x;
    const int lane = tid & 63;
    const int kq   = tid >> 6;          // wave id == k-quarter (wave-uniform)
    const int j0   = lane * 4;          // this lane's 4 output columns

    __shared__ __align__(16) float        x_lds[TT * DIN];     // 128 KB
    __shared__ __align__(16) float        part[4][HH];         // 4 KB
    __shared__ __align__(16) unsigned int hpk_lds[HH / 2];     // 512 B, fp16 pairs

    // ---- stage the whole x[b] into LDS (coalesced float4; once) ----
    {
        const float4* xg = (const float4*)(x + (size_t)b * TT * DIN);
        float4* xl = (float4*)x_lds;
        #pragma unroll 4
        for (int i = tid; i < TT * DIN / 4; i += NT) xl[i] = xg[i];
    }
    if (tid < HH / 2) hpk_lds[tid] = 0u;

    // ---- packed recurrent weights: w2[c][p] = (W[64kq+2p][j0+c], W[64kq+2p+1][j0+c])
    half2_t w2[4][32];
    #pragma unroll
    for (int p = 0; p < 32; ++p) {
        const float* r0 = W_rec + (size_t)(64 * kq + 2 * p) * HH + j0;
        const float* r1 = r0 + HH;
        #pragma unroll
        for (int c = 0; c < 4; ++c) {
            half2_t t2; t2.x = (_Float16)r0[c]; t2.y = (_Float16)r1[c];
            w2[c][p] = t2;
        }
    }

    // input-proj weights: this wave covers input dims [4kq, 4kq+4)
    float win[4][4];
    #pragma unroll
    for (int c = 0; c < 4; ++c) {
        #pragma unroll
        for (int r = 0; r < 4; ++r)
            win[c][r] = W_in[(size_t)(j0 + c) * DIN + 4 * kq + r];
    }

    // wave-0-only parameters for the LN/update tail
    float bi_[4], gi_[4], bbi_[4], itau_[4], gn_[4], bn_[4];
    float hj[4] = {0.f, 0.f, 0.f, 0.f};
    if (kq == 0) {
        const float4 v0 = *(const float4*)(b_in      + j0);
        const float4 v1 = *(const float4*)(g_intra   + j0);
        const float4 v2 = *(const float4*)(b_intra   + j0);
        const float4 v3 = *(const float4*)(tau_param + j0);
        const float4 v4 = *(const float4*)(g_norm    + j0);
        const float4 v5 = *(const float4*)(b_norm    + j0);
        bi_[0] = v0.x; bi_[1] = v0.y; bi_[2] = v0.z; bi_[3] = v0.w;
        gi_[0] = v1.x; gi_[1] = v1.y; gi_[2] = v1.z; gi_[3] = v1.w;
        bbi_[0] = v2.x; bbi_[1] = v2.y; bbi_[2] = v2.z; bbi_[3] = v2.w;
        itau_[0] = 1.f / softplus_f(v3.x); itau_[1] = 1.f / softplus_f(v3.y);
        itau_[2] = 1.f / softplus_f(v3.z); itau_[3] = 1.f / softplus_f(v3.w);
        gn_[0] = v4.x; gn_[1] = v4.y; gn_[2] = v4.z; gn_[3] = v4.w;
        bn_[0] = v5.x; bn_[1] = v5.y; bn_[2] = v5.z; bn_[3] = v5.w;
    }
    __syncthreads();

    for (int t = 0; t < TT; ++t) {
        // broadcast sources: x slice (same addr all lanes) + packed h pairs
        const float4 xs = *(const float4*)&x_lds[t * DIN + 4 * kq];
        const int hpk = (int)hpk_lds[kq * 32 + (lane & 31)];

        // ---- dot: 32 readlane, each feeding 4 dot2 (one per owned j)
        float a0 = 0.f, a1 = 0.f, a2 = 0.f, a3 = 0.f;
        #pragma unroll
        for (int p = 0; p < 32; ++p) {
            const int r = __builtin_amdgcn_readlane(hpk, p);
            a0 = __builtin_amdgcn_fdot2(as_h2(r), w2[0][p], a0, false);
            a1 = __builtin_amdgcn_fdot2(as_h2(r), w2[1][p], a1, false);
            a2 = __builtin_amdgcn_fdot2(as_h2(r), w2[2][p], a2, false);
            a3 = __builtin_amdgcn_fdot2(as_h2(r), w2[3][p], a3, false);
        }
        // ---- input projection for this wave's 4 input dims
        a0 = fmaf(xs.x, win[0][0], a0); a0 = fmaf(xs.y, win[0][1], a0);
        a0 = fmaf(xs.z, win[0][2], a0); a0 = fmaf(xs.w, win[0][3], a0);
        a1 = fmaf(xs.x, win[1][0], a1); a1 = fmaf(xs.y, win[1][1], a1);
        a1 = fmaf(xs.z, win[1][2], a1); a1 = fmaf(xs.w, win[1][3], a1);
        a2 = fmaf(xs.x, win[2][0], a2); a2 = fmaf(xs.y, win[2][1], a2);
        a2 = fmaf(xs.z, win[2][2], a2); a2 = fmaf(xs.w, win[2][3], a2);
        a3 = fmaf(xs.x, win[3][0], a3); a3 = fmaf(xs.y, win[3][1], a3);
        a3 = fmaf(xs.z, win[3][2], a3); a3 = fmaf(xs.w, win[3][3], a3);

        if (kq) ((float4*)part[kq])[lane] = make_float4(a0, a1, a2, a3);
        __syncthreads();   // A: partials visible (lgkmcnt-only drain)

        if (kq == 0) {
            const float4 p1 = ((const float4*)part[1])[lane];
            const float4 p2 = ((const float4*)part[2])[lane];
            const float4 p3 = ((const float4*)part[3])[lane];
            float u[4];
            u[0] = a0 + (p1.x + p2.x) + (p3.x + bi_[0]);
            u[1] = a1 + (p1.y + p2.y) + (p3.y + bi_[1]);
            u[2] = a2 + (p1.z + p2.z) + (p3.z + bi_[2]);
            u[3] = a3 + (p1.w + p2.w) + (p3.w + bi_[3]);
            float s1 = (u[0] + u[1]) + (u[2] + u[3]);
            float s2 = (u[0] * u[0] + u[1] * u[1]) + (u[2] * u[2] + u[3] * u[3]);
            wave_reduce2(s1, s2);
            const float S1 = rl63(s1);
            const float S2 = rl63(s2);
            const float mu  = S1 * (1.f / HH);
            const float var = S2 * (1.f / HH) - mu * mu;
            const float rs  = rsqrtf(var + LN_EPS_C);
            #pragma unroll
            for (int c = 0; c < 4; ++c) {
                const float xn = (u[c] - mu) * rs * gi_[c] + bbi_[c];
                // tanh(x) = 1 - 2/(exp(2x)+1); saturates correctly via inf/0
                const float e = __expf(2.f * xn);
                const float f = 1.f - 2.f / (e + 1.f);
                float v = hj[c] + (f - hj[c] * itau_[c]) * DT_STEP;
                v = fminf(10.f, fmaxf(-10.f, v));
                hj[c] = v;
            }
            uint2 pk;
            pk.x = __builtin_bit_cast(unsigned int, __builtin_amdgcn_cvt_pkrtz(hj[0], hj[1]));
            pk.y = __builtin_bit_cast(unsigned int, __builtin_amdgcn_cvt_pkrtz(hj[2], hj[3]));
            ((uint2*)hpk_lds)[lane] = pk;
        }
        __syncthreads();   // C: new packed h visible
    }

    // ---- final LayerNorm (g_norm, b_norm) + head ----
    if (kq == 0) {
        float s1 = (hj[0] + hj[1]) + (hj[2] + hj[3]);
        float s2 = (hj[0] * hj[0] + hj[1] * hj[1]) + (hj[2] * hj[2] + hj[3] * hj[3]);
        wave_reduce2(s1, s2);
        const float S1 = rl63(s1);
        const float S2 = rl63(s2);
        const float mu  = S1 * (1.f / HH);
        const float var = S2 * (1.f / HH) - mu * mu;
        const float rs  = rsqrtf(var + LN_EPS_C);
        float4 ho;
        ho.x = (hj[0] - mu) * rs * gn_[0] + bn_[0];
        ho.y = (hj[1] - mu) * rs * gn_[1] + bn_[1];
        ho.z = (hj[2] - mu) * rs * gn_[2] + bn_[2];
        ho.w = (hj[3] - mu) * rs * gn_[3] + bn_[3];
        ((float4*)part[0])[lane] = ho;
    }
    __syncthreads();
    if (tid < NAPP) {
        float o = b_head[tid];
        for (int jj = 0; jj < HH; ++jj)
            o = fmaf(part[0][jj], W_head[jj * NAPP + tid], o);
        out[(size_t)b * NAPP + tid] = o;
    }
}

extern "C" void kernel_launch(void* const* d_in, const int* in_sizes, int n_in,
                              void* d_out, int out_size, void* d_ws, size_t ws_size,
                              hipStream_t stream) {
    const float* x       = (const float*)d_in[0];
    const float* W_in    = (const float*)d_in[1];
    const float* b_in    = (const float*)d_in[2];
    const float* tau     = (const float*)d_in[3];
    const float* W_rec   = (const float*)d_in[4];
    const float* g_intra = (const float*)d_in[5];
    const float* b_intra = (const float*)d_in[6];
    const float* g_norm  = (const float*)d_in[7];
    const float* b_norm  = (const float*)d_in[8];
    const float* W_head  = (const float*)d_in[9];
    const float* b_head  = (const float*)d_in[10];
    float* out = (float*)d_out;

    hipLaunchKernelGGL(liquid_scan_kernel, dim3(BB), dim3(NT), 0, stream,
                       x, W_in, b_in, tau, W_rec, g_intra, b_intra,
                       g_norm, b_norm, W_head, b_head, out);
}